// Round 6
// baseline (73.124 us; speedup 1.0000x reference)
//
#include <hip/hip_runtime.h>

#define B_   64
#define C_   12
#define NC_  16
#define N0_  2048
#define N1_  1000
#define N2_  500
#define N3_  100
#define AGENT __HIP_MEMORY_SCOPE_AGENT

__device__ __forceinline__ float wred(float v) {
#pragma unroll
    for (int off = 32; off > 0; off >>= 1) v += __shfl_xor(v, off, 64);
    return v;
}

// ===== K1: h1 = relu(x·W1b^T + b1b). grid (63,12)×256, 4 rows/wave. =====
// Block (0,0) zeroes the K2 control region (y1acc/cntb/flag/cnt2/y2acc).
__global__ __launch_bounds__(256)
void k_l1b(const float* __restrict__ x, const int* __restrict__ cls,
           const float* __restrict__ W1b, const float* __restrict__ b1b,
           float* __restrict__ h1, int* __restrict__ zbase) {
    if (blockIdx.x == 0 && blockIdx.y == 0) {
        for (int i = threadIdx.x; i < 1408; i += 256) zbase[i] = 0;   // 5632 B
    }
    const int c    = blockIdx.y;
    const int lane = threadIdx.x & 63;
    const int wave = threadIdx.x >> 6;
    const unsigned long long m = __ballot(cls[lane] == c);
    if (m == 0ull) return;

    const int j0 = blockIdx.x * 16 + wave * 4;           // 4 consecutive rows
    if (j0 >= N1_) return;                                // 1000 % 4 == 0 -> clean tail

    const float* wbase = W1b + ((size_t)c * N1_ + j0) * N0_;
    float4 w[4][8];
#pragma unroll
    for (int k = 0; k < 4; ++k) {
        const float4* wr = (const float4*)(wbase + (size_t)k * N0_);
#pragma unroll
        for (int f = 0; f < 8; ++f) w[k][f] = wr[f * 64 + lane];
    }
    const float4 bias = *(const float4*)(b1b + c * N1_ + j0);

    for (unsigned long long mm = m; mm; mm &= (mm - 1ull)) {
        const int b = (int)__builtin_ctzll(mm);
        const float4* xr = (const float4*)(x + (size_t)b * N0_);
        float a0 = 0.f, a1 = 0.f, a2 = 0.f, a3 = 0.f;
#pragma unroll
        for (int f = 0; f < 8; ++f) {
            const float4 xv = xr[f * 64 + lane];
            a0 += w[0][f].x * xv.x + w[0][f].y * xv.y + w[0][f].z * xv.z + w[0][f].w * xv.w;
            a1 += w[1][f].x * xv.x + w[1][f].y * xv.y + w[1][f].z * xv.z + w[1][f].w * xv.w;
            a2 += w[2][f].x * xv.x + w[2][f].y * xv.y + w[2][f].z * xv.z + w[2][f].w * xv.w;
            a3 += w[3][f].x * xv.x + w[3][f].y * xv.y + w[3][f].z * xv.z + w[3][f].w * xv.w;
        }
        const float s0 = wred(a0), s1 = wred(a1), s2 = wred(a2), s3 = wred(a3);
        if (lane == 0) {
            float4 hv;
            hv.x = fmaxf(s0 + bias.x, 0.f);
            hv.y = fmaxf(s1 + bias.y, 0.f);
            hv.z = fmaxf(s2 + bias.z, 0.f);
            hv.w = fmaxf(s3 + bias.w, 0.f);
            *(float4*)(h1 + (size_t)b * N1_ + j0) = hv;   // 16B-aligned: 4000B row stride, j0%4==0
        }
    }
}

// ===== K2: 4 blocks per b (grid 256 × 1024). Block q owns rows j%4==q. =====
// h2-partial -> y1 atomics -> (last block) argmax+flag -> all blocks r-partial -> y2.
__global__ __launch_bounds__(1024)
void k_perb(const float* __restrict__ x, const int* __restrict__ cls,
            const float* __restrict__ h1,
            const float* __restrict__ W2b, const float* __restrict__ b2b,
            const float* __restrict__ W3b, const float* __restrict__ b3b,
            const float* __restrict__ W1r, const float* __restrict__ b1r,
            const float* __restrict__ W2r, const float* __restrict__ b2r,
            float* __restrict__ y1acc, int* __restrict__ cntb,
            int* __restrict__ flag,  int* __restrict__ cnt2,
            float* __restrict__ y2acc,
            float* __restrict__ out_y1, float* __restrict__ out_y2) {
    const int b    = blockIdx.x >> 2;
    const int q    = blockIdx.x & 3;
    const int tid  = threadIdx.x;
    const int lane = tid & 63;
    const int wave = tid >> 6;                     // 0..15
    const int c    = cls[b];

    __shared__ __align__(16) float s_x[N0_];       // 8 KB
    __shared__ __align__(16) float s_h1[N1_];      // 4 KB
    __shared__ float s_part[16][16];               // 1 KB
    __shared__ int   s_e;

    {
        const float4* xs = (const float4*)(x  + (size_t)b * N0_);
        const float4* hs = (const float4*)(h1 + (size_t)b * N1_);
        float4* xd = (float4*)s_x;
        float4* hd = (float4*)s_h1;
        if (tid < 512) xd[tid] = xs[tid];
        else if (tid < 512 + 250) hd[tid - 512] = hs[tid - 512];
    }
    __syncthreads();

    // ---- h2 rows j = 4*idx+q, idx in [0,125); partial y1 in lane<16 regs ----
    float accm = 0.f;
    for (int idx = wave; idx < 125; idx += 16) {
        const int j = 4 * idx + q;
        const float4* wr = (const float4*)(W2b + ((size_t)c * N2_ + j) * N1_);
        const float4* xr = (const float4*)s_h1;
        float a = 0.f;
#pragma unroll
        for (int f = 0; f < 4; ++f) {
            const int id4 = f * 64 + lane;
            if (id4 < N1_ / 4) {
                const float4 wv = wr[id4], xv = xr[id4];
                a += wv.x * xv.x + wv.y * xv.y + wv.z * xv.z + wv.w * xv.w;
            }
        }
        const float h2v = fmaxf(wred(a) + b2b[c * N2_ + j], 0.f);   // all lanes
        if (lane < NC_) accm += h2v * W3b[((size_t)c * NC_ + lane) * N2_ + j];
    }
    if (lane < NC_) s_part[wave][lane] = accm;
    __syncthreads();

    if (wave == 0) {
        if (lane < NC_) {
            float t = 0.f;
#pragma unroll
            for (int w = 0; w < 16; ++w) t += s_part[w][lane];
            __hip_atomic_fetch_add(&y1acc[b * NC_ + lane], t, __ATOMIC_RELAXED, AGENT);
        }
        int old = 0;
        if (lane == 0) old = __hip_atomic_fetch_add(&cntb[b], 1, __ATOMIC_ACQ_REL, AGENT);
        old = __shfl(old, 0, 64);
        if (old == 3) {                            // last of 4 blocks: finalize y1
            float v = -1e30f;
            if (lane < NC_) {
                v = __hip_atomic_load(&y1acc[b * NC_ + lane], __ATOMIC_RELAXED, AGENT)
                    + b3b[c * NC_ + lane];
                out_y1[b * NC_ + lane] = v;
            }
            int mi = lane;                          // first-occurrence argmax over 16
#pragma unroll
            for (int off = 8; off > 0; off >>= 1) {
                const float ov = __shfl_xor(v,  off, 16);
                const int   om = __shfl_xor(mi, off, 16);
                if (ov > v || (ov == v && om < mi)) { v = ov; mi = om; }
            }
            if (lane == 0)
                __hip_atomic_store(&flag[b], 1 + c * NC_ + mi, __ATOMIC_RELEASE, AGENT);
        }
        int fv = 0;
        if (lane == 0) {
            while ((fv = __hip_atomic_load(&flag[b], __ATOMIC_RELAXED, AGENT)) == 0)
                __builtin_amdgcn_s_sleep(1);
            s_e = fv - 1;
        }
    }
    __syncthreads();
    const int e = s_e;

    // ---- r rows j = 4*idx+q, idx in [0,25); partial y2 in lane<3 regs ----
    float y2p = 0.f;
    for (int idx = wave; idx < 25; idx += 16) {
        const int j = 4 * idx + q;
        const float4* wr = (const float4*)(W1r + ((size_t)e * N3_ + j) * N0_);
        const float4* xr = (const float4*)s_x;
        float a = 0.f;
#pragma unroll
        for (int f = 0; f < 8; ++f) {
            const int id4 = f * 64 + lane;
            const float4 wv = wr[id4], xv = xr[id4];
            a += wv.x * xv.x + wv.y * xv.y + wv.z * xv.z + wv.w * xv.w;
        }
        const float rv = fmaxf(wred(a) + b1r[e * N3_ + j], 0.f);    // all lanes
        if (lane < 3) y2p += rv * W2r[((size_t)e * 3 + lane) * N3_ + j];
    }
    if (lane < NC_) s_part[wave][lane] = (lane < 3) ? y2p : 0.f;
    __syncthreads();

    if (wave == 0) {
        if (lane < 3) {
            float t = 0.f;
#pragma unroll
            for (int w = 0; w < 16; ++w) t += s_part[w][lane];
            __hip_atomic_fetch_add(&y2acc[b * 3 + lane], t, __ATOMIC_RELAXED, AGENT);
        }
        int old = 0;
        if (lane == 0) old = __hip_atomic_fetch_add(&cnt2[b], 1, __ATOMIC_ACQ_REL, AGENT);
        old = __shfl(old, 0, 64);
        if (old == 3 && lane < 3) {                // last block finalizes y2
            const float vv = __hip_atomic_load(&y2acc[b * 3 + lane], __ATOMIC_RELAXED, AGENT);
            out_y2[b * 3 + lane] = vv + b2r[e * 3 + lane];
        }
    }
}

extern "C" void kernel_launch(void* const* d_in, const int* in_sizes, int n_in,
                              void* d_out, int out_size, void* d_ws, size_t ws_size,
                              hipStream_t stream) {
    const float* x   = (const float*)d_in[0];
    const int*   cls = (const int*)  d_in[1];
    const float* W1b = (const float*)d_in[2];
    const float* b1b = (const float*)d_in[3];
    const float* W2b = (const float*)d_in[4];
    const float* b2b = (const float*)d_in[5];
    const float* W3b = (const float*)d_in[6];
    const float* b3b = (const float*)d_in[7];
    const float* W1r = (const float*)d_in[8];
    const float* b1r = (const float*)d_in[9];
    const float* W2r = (const float*)d_in[10];
    const float* b2r = (const float*)d_in[11];

    float* out_y1 = (float*)d_out;                 // [0, 1024)
    float* out_y2 = (float*)d_out + B_ * NC_;      // [1024, 1216)

    char*  ws    = (char*)d_ws;
    float* h1    = (float*)(ws);                   // 256000 B
    // ---- control region zeroed by K1 block (0,0): 5632 B ----
    float* y1acc = (float*)(ws + 256000);          // 4096 B
    int*   cntb  = (int*)  (ws + 260096);          // 256 B
    int*   flag  = (int*)  (ws + 260352);          // 256 B
    int*   cnt2  = (int*)  (ws + 260608);          // 256 B
    float* y2acc = (float*)(ws + 260864);          // 768 B
    int*   zbase = (int*)  (ws + 256000);

    hipLaunchKernelGGL(k_l1b, dim3(63, 12), dim3(256), 0, stream,
                       x, cls, W1b, b1b, h1, zbase);
    hipLaunchKernelGGL(k_perb, dim3(256), dim3(1024), 0, stream,
                       x, cls, h1, W2b, b2b, W3b, b3b, W1r, b1r, W2r, b2r,
                       y1acc, cntb, flag, cnt2, y2acc, out_y1, out_y2);
}

// Round 7
// 69.825 us; speedup vs baseline: 1.0472x; 1.0472x over previous
//
#include <hip/hip_runtime.h>

#define B_   64
#define C_   12
#define NC_  16
#define N0_  2048
#define N1_  1000
#define N2_  500
#define N3_  100
#define AGENT __HIP_MEMORY_SCOPE_AGENT

__device__ __forceinline__ float wred(float v) {
#pragma unroll
    for (int off = 32; off > 0; off >>= 1) v += __shfl_xor(v, off, 64);
    return v;
}

// ===== K1: h1 = relu(x·W1b^T + b1b). grid (125,12)×256, 2 rows/wave (round-5 proven). =====
// Block (0,0) zeroes the 768 B K2 control region (cntb/cnt2/flag).
__global__ __launch_bounds__(256)
void k_l1b(const float* __restrict__ x, const int* __restrict__ cls,
           const float* __restrict__ W1b, const float* __restrict__ b1b,
           float* __restrict__ h1, int* __restrict__ zbase) {
    if (blockIdx.x == 0 && blockIdx.y == 0) {
        if (threadIdx.x < 192) zbase[threadIdx.x] = 0;
    }
    const int c    = blockIdx.y;
    const int lane = threadIdx.x & 63;
    const int wave = threadIdx.x >> 6;
    const unsigned long long m = __ballot(cls[lane] == c);
    if (m == 0ull) return;

    const int j0 = blockIdx.x * 8 + wave * 2;                 // < 1000 always
    const float4* wr0 = (const float4*)(W1b + ((size_t)c * N1_ + j0) * N0_);
    const float4* wr1 = wr0 + (N0_ / 4);
    float4 w0[8], w1[8];
#pragma unroll
    for (int f = 0; f < 8; ++f) { w0[f] = wr0[f * 64 + lane]; w1[f] = wr1[f * 64 + lane]; }
    const float bias0 = b1b[c * N1_ + j0];
    const float bias1 = b1b[c * N1_ + j0 + 1];

    for (unsigned long long mm = m; mm; mm &= (mm - 1ull)) {
        const int b = (int)__builtin_ctzll(mm);
        const float4* xr = (const float4*)(x + (size_t)b * N0_);
        float a0 = 0.f, a1 = 0.f;
#pragma unroll
        for (int f = 0; f < 8; ++f) {
            const float4 xv = xr[f * 64 + lane];
            a0 += w0[f].x * xv.x + w0[f].y * xv.y + w0[f].z * xv.z + w0[f].w * xv.w;
            a1 += w1[f].x * xv.x + w1[f].y * xv.y + w1[f].z * xv.z + w1[f].w * xv.w;
        }
        const float s0 = wred(a0), s1 = wred(a1);
        if (lane == 0) {
            h1[(size_t)b * N1_ + j0]     = fmaxf(s0 + bias0, 0.f);
            h1[(size_t)b * N1_ + j0 + 1] = fmaxf(s1 + bias1, 0.f);
        }
    }
}

// ===== K2: 4 blocks per b (grid 256 × 1024). Block q owns rows j%4==q. =====
// Plain-store partials + fence + ACQ_REL counter; last block finalizes. W3b slice in LDS.
__global__ __launch_bounds__(1024)
void k_perb(const float* __restrict__ x, const int* __restrict__ cls,
            const float* __restrict__ h1,
            const float* __restrict__ W2b, const float* __restrict__ b2b,
            const float* __restrict__ W3b, const float* __restrict__ b3b,
            const float* __restrict__ W1r, const float* __restrict__ b1r,
            const float* __restrict__ W2r, const float* __restrict__ b2r,
            float* __restrict__ y1part, float* __restrict__ y2part,
            int* __restrict__ cntb, int* __restrict__ cnt2, int* __restrict__ flag,
            float* __restrict__ out_y1, float* __restrict__ out_y2) {
    const int b    = blockIdx.x >> 2;
    const int q    = blockIdx.x & 3;
    const int tid  = threadIdx.x;
    const int lane = tid & 63;
    const int wave = tid >> 6;                     // 0..15
    const int c    = cls[b];

    __shared__ __align__(16) float s_x[N0_];       // 8 KB
    __shared__ __align__(16) float s_h1[N1_];      // 4 KB
    __shared__ float s_w3[NC_][125];               // 8 KB (stride 125 odd -> conflict-free)
    __shared__ float s_part[16][16];               // 1 KB
    __shared__ int   s_e;

    {
        const float4* xs = (const float4*)(x  + (size_t)b * N0_);
        const float4* hs = (const float4*)(h1 + (size_t)b * N1_);
        if (tid < 512) ((float4*)s_x)[tid] = xs[tid];
        else if (tid < 512 + 250) ((float4*)s_h1)[tid - 512] = hs[tid - 512];
    }
    for (int i = tid; i < NC_ * 125; i += 1024) {  // W3b[c][m][4*idx+q]
        const int mi = i / 125, idx = i - mi * 125;
        s_w3[mi][idx] = W3b[((size_t)c * NC_ + mi) * N2_ + 4 * idx + q];
    }
    __syncthreads();

    // ---- P2: h2 rows j = 4*idx+q; y1 partials in lane<16 regs ----
    float accm = 0.f;
    for (int idx = wave; idx < 125; idx += 16) {
        const int j = 4 * idx + q;
        const float4* wr = (const float4*)(W2b + ((size_t)c * N2_ + j) * N1_);
        const float4* xr = (const float4*)s_h1;
        float a = 0.f;
#pragma unroll
        for (int f = 0; f < 4; ++f) {
            const int id4 = f * 64 + lane;
            if (id4 < N1_ / 4) {
                const float4 wv = wr[id4], xv = xr[id4];
                a += wv.x * xv.x + wv.y * xv.y + wv.z * xv.z + wv.w * xv.w;
            }
        }
        const float h2v = fmaxf(wred(a) + b2b[c * N2_ + j], 0.f);   // all lanes
        if (lane < NC_) accm += h2v * s_w3[lane][idx];
    }
    if (lane < NC_) s_part[wave][lane] = accm;
    __syncthreads();

    if (wave == 0) {
        if (lane < NC_) {
            float t = 0.f;
#pragma unroll
            for (int w = 0; w < 16; ++w) t += s_part[w][lane];
            y1part[(size_t)(b * 4 + q) * NC_ + lane] = t;           // plain store
        }
        __threadfence();
        int old = 0;
        if (lane == 0) old = __hip_atomic_fetch_add(&cntb[b], 1, __ATOMIC_ACQ_REL, AGENT);
        old = __shfl(old, 0, 64);
        if (old == 3) {                            // last of 4 blocks: finalize y1
            float v = -1e30f;
            if (lane < NC_) {
                v = b3b[c * NC_ + lane];
#pragma unroll
                for (int qq = 0; qq < 4; ++qq) v += y1part[(size_t)(b * 4 + qq) * NC_ + lane];
                out_y1[b * NC_ + lane] = v;
            }
            int mi = lane;                          // first-occurrence argmax over 16
#pragma unroll
            for (int off = 8; off > 0; off >>= 1) {
                const float ov = __shfl_xor(v,  off, 16);
                const int   om = __shfl_xor(mi, off, 16);
                if (ov > v || (ov == v && om < mi)) { v = ov; mi = om; }
            }
            if (lane == 0)
                __hip_atomic_store(&flag[b], 1 + c * NC_ + mi, __ATOMIC_RELEASE, AGENT);
        }
        int fv = 0;
        if (lane == 0) {
            while ((fv = __hip_atomic_load(&flag[b], __ATOMIC_RELAXED, AGENT)) == 0)
                __builtin_amdgcn_s_sleep(1);
            s_e = fv - 1;
        }
    }
    __syncthreads();
    const int e = s_e;

    // ---- P4: r rows j = 4*idx+q; y2 partials in lane<3 regs ----
    float y2p = 0.f;
    for (int idx = wave; idx < 25; idx += 16) {
        const int j = 4 * idx + q;
        const float4* wr = (const float4*)(W1r + ((size_t)e * N3_ + j) * N0_);
        const float4* xr = (const float4*)s_x;
        float a = 0.f;
#pragma unroll
        for (int f = 0; f < 8; ++f) {
            const int id4 = f * 64 + lane;
            const float4 wv = wr[id4], xv = xr[id4];
            a += wv.x * xv.x + wv.y * xv.y + wv.z * xv.z + wv.w * xv.w;
        }
        const float rv = fmaxf(wred(a) + b1r[e * N3_ + j], 0.f);    // all lanes
        if (lane < 3) y2p += rv * W2r[((size_t)e * 3 + lane) * N3_ + j];
    }
    if (lane < NC_) s_part[wave][lane] = (lane < 3) ? y2p : 0.f;
    __syncthreads();

    if (wave == 0) {
        if (lane < 3) {
            float t = 0.f;
#pragma unroll
            for (int w = 0; w < 16; ++w) t += s_part[w][lane];
            y2part[(size_t)(b * 4 + q) * 3 + lane] = t;             // plain store
        }
        __threadfence();
        int old = 0;
        if (lane == 0) old = __hip_atomic_fetch_add(&cnt2[b], 1, __ATOMIC_ACQ_REL, AGENT);
        old = __shfl(old, 0, 64);
        if (old == 3 && lane < 3) {                // last block finalizes y2
            float t = b2r[e * 3 + lane];
#pragma unroll
            for (int qq = 0; qq < 4; ++qq) t += y2part[(size_t)(b * 4 + qq) * 3 + lane];
            out_y2[b * 3 + lane] = t;
        }
    }
}

extern "C" void kernel_launch(void* const* d_in, const int* in_sizes, int n_in,
                              void* d_out, int out_size, void* d_ws, size_t ws_size,
                              hipStream_t stream) {
    const float* x   = (const float*)d_in[0];
    const int*   cls = (const int*)  d_in[1];
    const float* W1b = (const float*)d_in[2];
    const float* b1b = (const float*)d_in[3];
    const float* W2b = (const float*)d_in[4];
    const float* b2b = (const float*)d_in[5];
    const float* W3b = (const float*)d_in[6];
    const float* b3b = (const float*)d_in[7];
    const float* W1r = (const float*)d_in[8];
    const float* b1r = (const float*)d_in[9];
    const float* W2r = (const float*)d_in[10];
    const float* b2r = (const float*)d_in[11];

    float* out_y1 = (float*)d_out;                 // [0, 1024)
    float* out_y2 = (float*)d_out + B_ * NC_;      // [1024, 1216)

    char*  ws     = (char*)d_ws;
    float* h1     = (float*)(ws);                  // 256000 B
    float* y1part = (float*)(ws + 256000);         // 256*16*4 = 16384 B
    float* y2part = (float*)(ws + 272384);         // 256*3*4  =  3072 B
    // ---- control region zeroed by K1 block (0,0): 768 B ----
    int*   cntb   = (int*)  (ws + 275456);         // 256 B
    int*   cnt2   = (int*)  (ws + 275712);         // 256 B
    int*   flag   = (int*)  (ws + 275968);         // 256 B
    int*   zbase  = (int*)  (ws + 275456);

    hipLaunchKernelGGL(k_l1b, dim3(125, 12), dim3(256), 0, stream,
                       x, cls, W1b, b1b, h1, zbase);
    hipLaunchKernelGGL(k_perb, dim3(256), dim3(1024), 0, stream,
                       x, cls, h1, W2b, b2b, W3b, b3b, W1r, b1r, W2r, b2r,
                       y1part, y2part, cntb, cnt2, flag, out_y1, out_y2);
}